// Round 13
// baseline (355.571 us; speedup 1.0000x reference)
//
#include <hip/hip_runtime.h>
#include <hip/hip_bf16.h>

#define BB 8
#define TSEQ 8192
#define DDIM 512
#define NH 4
#define HDIM 128
#define NP 24
#define NPAD 32
#define NTOPK 12
#define NCHUNK 32
#define TCHUNK 256
#define NTILES 8

typedef _Float16 half8_t __attribute__((ext_vector_type(8)));
typedef _Float16 half4_t __attribute__((ext_vector_type(4)));
typedef _Float16 half2_t __attribute__((ext_vector_type(2)));
typedef float f32x4_t __attribute__((ext_vector_type(4)));

#define MFMA(a, b, c) __builtin_amdgcn_mfma_f32_16x16x32_f16((a), (b), (c), 0, 0, 0)

// LDS-only barrier: keeps global loads in flight across phases.
#define WGBAR() do { asm volatile("s_waitcnt lgkmcnt(0)" ::: "memory"); \
                     __builtin_amdgcn_s_barrier(); } while (0)

// ws layout (f32 units):
// qhs@0(12288) ml@12288(65536) xbar16@77824(8388608) pt@8466432(98304)
// wg16@8564736(131072) wqkg16@8695808(32768)
// uvK@9121792(512) vvK@9122304(512) uq@9122816(128) vq@9122944(128)
// zbuf@9123072(4096) hbuf@9127168(4096)

// ---------------- Qh precompute (unchanged) ----------------
__global__ __launch_bounds__(256) void qh_kernel(
    const float* __restrict__ proto, const float* __restrict__ Wq, float* __restrict__ qhs)
{
  const int p = blockIdx.x, tid = threadIdx.x;
  __shared__ float prow[DDIM];
  __shared__ float qp[DDIM];
  __shared__ float np[NH][8];
  __shared__ float nb[NH];
  prow[tid] = proto[(size_t)p * DDIM + tid];
  prow[tid + 256] = proto[(size_t)p * DDIM + tid + 256];
  __syncthreads();
#pragma unroll
  for (int i = 0; i < 2; ++i) {
    int dd = tid + i * 256;
    const float4* w4 = reinterpret_cast<const float4*>(Wq + (size_t)dd * DDIM);
    const float4* p4 = reinterpret_cast<const float4*>(prow);
    float s = 0.f;
    for (int d = 0; d < 128; ++d) {
      float4 av = p4[d], bv = w4[d];
      s += av.x * bv.x + av.y * bv.y + av.z * bv.z + av.w * bv.w;
    }
    qp[dd] = s;
  }
  __syncthreads();
  {
    int hh = tid >> 3, pr = tid & 7;
    if (hh < NH) {
      float s = 0.f;
      for (int k = 0; k < 16; ++k) { float v = qp[hh * HDIM + pr * 16 + k]; s += v * v; }
      np[hh][pr] = s;
    }
  }
  __syncthreads();
  if (tid < NH) {
    float s = 0.f;
    for (int k = 0; k < 8; ++k) s += np[tid][k];
    nb[tid] = 1.f / (fmaxf(sqrtf(s), 1e-12f) * 0.07f);
  }
  __syncthreads();
#pragma unroll
  for (int i = 0; i < 2; ++i) {
    int dd = tid + i * 256;
    int hh = dd >> 7, jj = dd & 127;
    qhs[((size_t)hh * NP + p) * HDIM + jj] = qp[dd] * nb[hh];
  }
}

// ---------------- wg16 = Wk*g (f16); u[j]=Wk.g, v[j]=Wk.b (f32) ----------------
__global__ __launch_bounds__(256) void wg16_kernel(
    const float* __restrict__ Wk, const float* __restrict__ ln_g, const float* __restrict__ ln_b,
    _Float16* __restrict__ wg16, float* __restrict__ uvK, float* __restrict__ vvK)
{
  const int j = blockIdx.x, tid = threadIdx.x;
  __shared__ float su[256], sv[256];
  float w0 = Wk[(size_t)j * 512 + tid], w1 = Wk[(size_t)j * 512 + tid + 256];
  float g0 = ln_g[tid], g1 = ln_g[tid + 256];
  float b0 = ln_b[tid], b1 = ln_b[tid + 256];
  wg16[(size_t)j * 512 + tid] = (_Float16)(w0 * g0);
  wg16[(size_t)j * 512 + tid + 256] = (_Float16)(w1 * g1);
  su[tid] = w0 * g0 + w1 * g1;
  sv[tid] = w0 * b0 + w1 * b1;
  __syncthreads();
  for (int s = 128; s > 0; s >>= 1) {
    if (tid < s) { su[tid] += su[tid + s]; sv[tid] += sv[tid + s]; }
    __syncthreads();
  }
  if (tid == 0) { uvK[j] = su[0]; vvK[j] = sv[0]; }
}

// ---------------- wqkg16 = (qhs@Wk)*g (f16); uq,vq reductions ----------------
__global__ __launch_bounds__(256) void wqkg_kernel(
    const float* __restrict__ qhs, const float* __restrict__ Wk,
    const float* __restrict__ ln_g, const float* __restrict__ ln_b,
    _Float16* __restrict__ wqkg16, float* __restrict__ uq, float* __restrict__ vq)
{
  const int blk = blockIdx.x, tid = threadIdx.x;
  const int p = blk & 31, h = blk >> 5;
  __shared__ float su[256], sv[256];
  if (p >= NP) {
    wqkg16[((size_t)(h * 32 + p)) * 512 + tid] = (_Float16)0.f;
    wqkg16[((size_t)(h * 32 + p)) * 512 + tid + 256] = (_Float16)0.f;
    if (tid == 0) { uq[h * 32 + p] = 0.f; vq[h * 32 + p] = 0.f; }
    return;
  }
  __shared__ float qv[HDIM];
  if (tid < HDIM) qv[tid] = qhs[((size_t)h * NP + p) * HDIM + tid];
  __syncthreads();
  float s0 = 0.f, s1 = 0.f;
  for (int j = 0; j < HDIM; ++j) {
    float q = qv[j];
    const float* wr = Wk + (size_t)(h * 128 + j) * 512;
    s0 += q * wr[tid];
    s1 += q * wr[tid + 256];
  }
  float g0 = ln_g[tid], g1 = ln_g[tid + 256];
  float b0 = ln_b[tid], b1 = ln_b[tid + 256];
  wqkg16[((size_t)(h * 32 + p)) * 512 + tid] = (_Float16)(s0 * g0);
  wqkg16[((size_t)(h * 32 + p)) * 512 + tid + 256] = (_Float16)(s1 * g1);
  su[tid] = s0 * g0 + s1 * g1;
  sv[tid] = s0 * b0 + s1 * b1;
  __syncthreads();
  for (int s = 128; s > 0; s >>= 1) {
    if (tid < s) { su[tid] += su[tid + s]; sv[tid] += sv[tid + s]; }
    __syncthreads();
  }
  if (tid == 0) { uq[h * 32 + p] = su[0]; vq[h * 32 + p] = sv[0]; }
}

// ---------------- attn7: fused K-norm (waves 4-7) + scores/softmax (waves 0-3)
//                  + accumulate (all), LN-commuted, raw-x staged once.
// grid [b8][g2 2][c32] = 512 blocks, 512 thr.
__global__ __launch_bounds__(512, 1) void attn7(
    const float* __restrict__ x, const _Float16* __restrict__ wg16,
    const _Float16* __restrict__ wqkg16,
    const float* __restrict__ uvK, const float* __restrict__ vvK,
    const float* __restrict__ uq, const float* __restrict__ vq,
    const float* __restrict__ ln_g, const float* __restrict__ ln_b,
    float* __restrict__ ml, _Float16* __restrict__ xbar)
{
  const int tid = threadIdx.x;
  const int w = tid >> 6, l = tid & 63;
  const int g = l >> 4, a = l & 15;
  const int blk = blockIdx.x;
  const int c = blk & 31, g2 = (blk >> 5) & 1, b = blk >> 6;

  __shared__ __align__(16) unsigned char xs_raw[32 * 1040];   // [32 t][520 f16] raw x
  __shared__ __align__(16) unsigned char xt_raw[512 * 72];    // [512 d][36 f16], quad-swizzled
  __shared__ __align__(16) unsigned char wl_raw[64 * 80];     // [64 p][40 f16]
  __shared__ float mArr_s[64], lArr_s[64], fbuf_s[64], c1Arr_s[64];
  __shared__ float normp_s[4][32];                            // [q][t] K-norm partials (64 j each)
  __shared__ float2 miv_s[32];                                // per-token (mu, iv)

  if (tid < 64) { mArr_s[tid] = -1e30f; lArr_s[tid] = 0.f; c1Arr_s[tid] = 0.f; }

  f32x4_t acc3[4][4];
  const f32x4_t vzero = {0.f, 0.f, 0.f, 0.f};
#pragma unroll
  for (int mA = 0; mA < 4; ++mA)
#pragma unroll
    for (int nt = 0; nt < 4; ++nt) acc3[mA][nt] = vzero;

  const float4* xc4 = reinterpret_cast<const float4*>(x) + ((size_t)(b * TSEQ + c * TCHUNK)) * 128;
  // waves 0-3: G2 weights; waves 4-7: G1 weights (64 j per wave, streamed from L2)
  const _Float16* wqbase = wqkg16 + ((size_t)(g2 * 64 + 16 * w + a)) * 512 + g * 8;   // w<4
  const int q = w & 3;                                         // w>=4: j-quarter
  const int jrow0 = g2 * 256 + 64 * q + a;                     // + 16*nt
  float uqp = 0.f, vqp = 0.f;
  float uK[4], vK[4];
  if (w < 4) {
    uqp = uq[g2 * 64 + 16 * w + a];
    vqp = vq[g2 * 64 + 16 * w + a];
  } else {
#pragma unroll
    for (int nt = 0; nt < 4; ++nt) { uK[nt] = uvK[jrow0 + 16 * nt]; vK[nt] = vvK[jrow0 + 16 * nt]; }
  }

  float4 praw[4][2];
#pragma unroll
  for (int tt = 0; tt < 4; ++tt)
#pragma unroll
    for (int i = 0; i < 2; ++i)
      praw[tt][i] = xc4[(size_t)(4 * w + tt) * 128 + l + 64 * i];

  for (int tile = 0; tile < NTILES; ++tile) {
    // ---- LN stats on raw f32 (all waves, own 4 tokens) ----
    float sA[4], sB[4];
#pragma unroll
    for (int tt = 0; tt < 4; ++tt) {
      float4 v0f = praw[tt][0], v1f = praw[tt][1];
      sA[tt] = (v0f.x + v0f.y) + (v0f.z + v0f.w) + (v1f.x + v1f.y) + (v1f.z + v1f.w);
      sB[tt] = (v0f.x * v0f.x + v0f.y * v0f.y) + (v0f.z * v0f.z + v0f.w * v0f.w)
             + (v1f.x * v1f.x + v1f.y * v1f.y) + (v1f.z * v1f.z + v1f.w * v1f.w);
    }
#pragma unroll
    for (int m = 1; m < 64; m <<= 1)
#pragma unroll
      for (int tt = 0; tt < 4; ++tt) { sA[tt] += __shfl_xor(sA[tt], m); sB[tt] += __shfl_xor(sB[tt], m); }
    float muv[4], ivv[4];
#pragma unroll
    for (int tt = 0; tt < 4; ++tt) {
      float mu = sA[tt] * (1.f / 512.f);
      float var = sB[tt] * (1.f / 512.f) - mu * mu;
      muv[tt] = mu; ivv[tt] = rsqrtf(var + 1e-5f);
    }

    WGBAR();   // barA: prev tile's GEMM reads of xs/xt done

    // ---- stage raw x: xs (d-contig) + xt (t-contig, swizzled); publish miv_s ----
#pragma unroll
    for (int tt = 0; tt < 4; ++tt)
#pragma unroll
      for (int i = 0; i < 2; ++i) {
        float4 v = praw[tt][i];
        half4_t hx;
        hx[0] = (_Float16)v.x; hx[1] = (_Float16)v.y; hx[2] = (_Float16)v.z; hx[3] = (_Float16)v.w;
        *reinterpret_cast<half4_t*>(xs_raw + (4 * w + tt) * 1040 + 8 * l + 512 * i) = hx;
      }
    {
      const float* pf = reinterpret_cast<const float*>(praw);
#pragma unroll
      for (int i = 0; i < 2; ++i)
#pragma unroll
        for (int e = 0; e < 4; ++e) {
          half4_t hv;
          hv[0] = (_Float16)pf[0 * 8 + i * 4 + e];
          hv[1] = (_Float16)pf[1 * 8 + i * 4 + e];
          hv[2] = (_Float16)pf[2 * 8 + i * 4 + e];
          hv[3] = (_Float16)pf[3 * 8 + i * 4 + e];
          int d = 4 * l + 256 * i + e;
          *reinterpret_cast<half4_t*>(xt_raw + d * 72 + 8 * (w ^ ((d >> 4) & 7))) = hv;
        }
    }
#pragma unroll
    for (int tt = 0; tt < 4; ++tt)
      if (l == tt) miv_s[4 * w + tt] = make_float2(muv[tt], ivv[tt]);
    // ---- prefetch next tile (stays in flight across barriers) ----
    if (tile + 1 < NTILES) {
#pragma unroll
      for (int tt = 0; tt < 4; ++tt)
#pragma unroll
        for (int i = 0; i < 2; ++i)
          praw[tt][i] = xc4[(size_t)((tile + 1) * 32 + 4 * w + tt) * 128 + l + 64 * i];
    }
    WGBAR();   // barB: xs/xt/miv ready

    f32x4_t qacc[2] = {vzero, vzero};
    if (w < 4) {
      // ---- G2: raw scores (16 p x 32 t per wave) ----
#pragma unroll
      for (int kst = 0; kst < 16; ++kst) {
        half8_t bq8 = *reinterpret_cast<const half8_t*>(wqbase + kst * 32);
#pragma unroll
        for (int mt = 0; mt < 2; ++mt) {
          half8_t af = *reinterpret_cast<const half8_t*>(xs_raw + (16 * mt + a) * 1040 + kst * 64 + g * 16);
          qacc[mt] = MFMA(af, bq8, qacc[mt]);
        }
      }
    } else {
      // ---- G1: K-projection for this wave's 64 j; LN-commute; norm partials ----
      f32x4_t kacc[2][4];
#pragma unroll
      for (int mt = 0; mt < 2; ++mt)
#pragma unroll
        for (int nt = 0; nt < 4; ++nt) kacc[mt][nt] = vzero;
#pragma unroll
      for (int kst = 0; kst < 16; ++kst) {
        half8_t bnt[4];
#pragma unroll
        for (int nt = 0; nt < 4; ++nt)
          bnt[nt] = *reinterpret_cast<const half8_t*>(
              wg16 + (size_t)(jrow0 + 16 * nt) * 512 + kst * 32 + g * 8);
#pragma unroll
        for (int mt = 0; mt < 2; ++mt) {
          half8_t af = *reinterpret_cast<const half8_t*>(xs_raw + (16 * mt + a) * 1040 + kst * 64 + g * 16);
#pragma unroll
          for (int nt = 0; nt < 4; ++nt) kacc[mt][nt] = MFMA(af, bnt[nt], kacc[mt][nt]);
        }
      }
      float np2[2][4];
#pragma unroll
      for (int mt = 0; mt < 2; ++mt)
#pragma unroll
        for (int r = 0; r < 4; ++r) {
          float2 mvt = miv_s[16 * mt + 4 * g + r];
          float s = 0.f;
#pragma unroll
          for (int nt = 0; nt < 4; ++nt) {
            float k = mvt.y * (kacc[mt][nt][r] - mvt.x * uK[nt]) + vK[nt];
            s += k * k;
          }
          np2[mt][r] = s;
        }
#pragma unroll
      for (int m = 1; m < 16; m <<= 1)
#pragma unroll
        for (int mt = 0; mt < 2; ++mt)
#pragma unroll
          for (int r = 0; r < 4; ++r) np2[mt][r] += __shfl_xor(np2[mt][r], m);
      if (a == 0) {
#pragma unroll
        for (int mt = 0; mt < 2; ++mt)
#pragma unroll
          for (int r = 0; r < 4; ++r) normp_s[q][16 * mt + 4 * g + r] = np2[mt][r];
      }
    }
    WGBAR();   // barN: norm partials ready

    // ---- softmax (waves 0-3; col p = 16w + a) ----
    if (w < 4) {
      const int hl = w >> 1;
      const int p = 16 * w + a;
      float sc[2][4], ivr[2][4], imr[2][4];
      float cmax = -3e38f;
#pragma unroll
      for (int mt = 0; mt < 2; ++mt)
#pragma unroll
        for (int r = 0; r < 4; ++r) {
          const int t = 16 * mt + 4 * g + r;
          float2 mvt = miv_s[t];
          float n2 = normp_s[2 * hl][t] + normp_s[2 * hl + 1][t];
          float niv = rsqrtf(fmaxf(n2, 1e-24f));
          ivr[mt][r] = mvt.y;
          imr[mt][r] = mvt.y * mvt.x;
          float s = (mvt.y * (qacc[mt][r] - mvt.x * uqp) + vqp) * niv;
          sc[mt][r] = s;
          cmax = fmaxf(cmax, s);
        }
      cmax = fmaxf(cmax, __shfl_xor(cmax, 16));
      cmax = fmaxf(cmax, __shfl_xor(cmax, 32));
      float mo = mArr_s[p];
      float mn = fmaxf(mo, cmax);
      float fe = __expf(mo - mn);
      float ls = 0.f, ls1 = 0.f;
#pragma unroll
      for (int mt = 0; mt < 2; ++mt) {
        half4_t wp;
#pragma unroll
        for (int r = 0; r < 4; ++r) {
          float e = __expf(sc[mt][r] - mn);
          ls += e;
          ls1 += e * imr[mt][r];
          wp[r] = (_Float16)(e * ivr[mt][r]);   // weight for raw-x accumulate
        }
        *reinterpret_cast<half4_t*>(wl_raw + p * 80 + 32 * mt + 8 * g) = wp;
      }
      ls += __shfl_xor(ls, 16);   ls += __shfl_xor(ls, 32);
      ls1 += __shfl_xor(ls1, 16); ls1 += __shfl_xor(ls1, 32);
      if (l < 16) {
        mArr_s[p] = mn;
        lArr_s[p] = lArr_s[p] * fe + ls;
        c1Arr_s[p] = c1Arr_s[p] * fe + ls1;
        fbuf_s[p] = fe;
      }
    }
    WGBAR();   // barE: wl + fbuf ready

    // ---- rescale acc + G3 (accumulate Σ (e·iv)·x_raw) ----
#pragma unroll
    for (int mA = 0; mA < 4; ++mA)
#pragma unroll
      for (int r = 0; r < 4; ++r) {
        float f = fbuf_s[16 * mA + 4 * g + r];
#pragma unroll
        for (int nt = 0; nt < 4; ++nt) acc3[mA][nt][r] *= f;
      }
    {
      half8_t wlf[4];
#pragma unroll
      for (int mA = 0; mA < 4; ++mA)
        wlf[mA] = *reinterpret_cast<const half8_t*>(wl_raw + (16 * mA + a) * 80 + 16 * g);
#pragma unroll
      for (int nt = 0; nt < 4; ++nt) {
        const int d = 64 * w + 16 * nt + a;
        const unsigned char* rowp = xt_raw + d * 72;
        const int key = (d >> 4) & 7;
        half4_t lo = *reinterpret_cast<const half4_t*>(rowp + 8 * ((2 * g) ^ key));
        half4_t hi = *reinterpret_cast<const half4_t*>(rowp + 8 * ((2 * g + 1) ^ key));
        half8_t bf;
        bf[0] = lo[0]; bf[1] = lo[1]; bf[2] = lo[2]; bf[3] = lo[3];
        bf[4] = hi[0]; bf[5] = hi[1]; bf[6] = hi[2]; bf[7] = hi[3];
#pragma unroll
        for (int mA = 0; mA < 4; ++mA) acc3[mA][nt] = MFMA(wlf[mA], bf, acc3[mA][nt]);
      }
    }
  }

  __syncthreads();
  // ---- epilogue: xb = g*(acc - c1) + b*l  (recovers Σ e·xn exactly) ----
  float gd[4], bd[4];
#pragma unroll
  for (int nt = 0; nt < 4; ++nt) {
    gd[nt] = ln_g[64 * w + 16 * nt + a];
    bd[nt] = ln_b[64 * w + 16 * nt + a];
  }
#pragma unroll
  for (int mA = 0; mA < 4; ++mA)
#pragma unroll
    for (int r = 0; r < 4; ++r) {
      const int p = 16 * mA + 4 * g + r;
      const float c1p = c1Arr_s[p], lp = lArr_s[p];
      const int h = 2 * g2 + (p >> 5), ph = p & 31;
      _Float16* xb = xbar + ((((size_t)b * NH + h) * NCHUNK + c) * NPAD + ph) * DDIM;
#pragma unroll
      for (int nt = 0; nt < 4; ++nt)
        xb[64 * w + 16 * nt + a] = (_Float16)(gd[nt] * (acc3[mA][nt][r] - c1p) + bd[nt] * lp);
    }
  if (tid < 64) {
    const int h = 2 * g2 + (tid >> 5), ph = tid & 31;
    size_t mlb = ((((size_t)b * NH + h) * NCHUNK + c) * NPAD + ph) * 2;
    ml[mlb] = mArr_s[tid];
    ml[mlb + 1] = lArr_s[tid];
  }
}

// ---------------- combine chunk partials, apply Wv (coalesced wave-dot) --------
__global__ __launch_bounds__(256) void reduce_proto(
    const float* __restrict__ ml, const _Float16* __restrict__ xbar,
    const float* __restrict__ Wv, float* __restrict__ proto_t)
{
  const int tid = threadIdx.x;
  const int blk = blockIdx.x;
  const int p = blk % NP;
  const int h = (blk / NP) % NH;
  const int b = blk / (NP * NH);
  const int wv = tid >> 6, ln = tid & 63;

  __shared__ float fch[NCHUNK];
  __shared__ float LinvS;
  __shared__ __align__(16) float xbs[DDIM];

  if (tid < NCHUNK) {
    size_t idx = ((((size_t)b * NH + h) * NCHUNK + tid) * NPAD + p) * 2;
    float m = ml[idx], lv = ml[idx + 1];
    float mstar = m;
#pragma unroll
    for (int k = 16; k >= 1; k >>= 1) mstar = fmaxf(mstar, __shfl_xor(mstar, k));
    float f = __expf(m - mstar);
    float Lp = lv * f;
#pragma unroll
    for (int k = 16; k >= 1; k >>= 1) Lp += __shfl_xor(Lp, k);
    fch[tid] = f;
    if (tid == 0) LinvS = 1.f / fmaxf(Lp, 1e-30f);
  }
  __syncthreads();
  float a0 = 0.f, a1 = 0.f;
  for (int cc = 0; cc < NCHUNK; ++cc) {
    float f = fch[cc];
    const _Float16* src = xbar + ((((size_t)b * NH + h) * NCHUNK + cc) * NPAD + p) * DDIM;
    half2_t v = *reinterpret_cast<const half2_t*>(src + 2 * tid);
    a0 += f * (float)v[0];
    a1 += f * (float)v[1];
  }
  xbs[2 * tid] = a0;
  xbs[2 * tid + 1] = a1;
  __syncthreads();
  const float Linv = LinvS;
  const float4* zp = reinterpret_cast<const float4*>(xbs);
  const float4 z0 = zp[2 * ln], z1 = zp[2 * ln + 1];
#pragma unroll 4
  for (int j0 = 0; j0 < 32; ++j0) {
    const int j = wv * 32 + j0;
    const float4* wrow = reinterpret_cast<const float4*>(Wv + (size_t)(h * HDIM + j) * DDIM);
    float4 w0 = wrow[2 * ln], w1 = wrow[2 * ln + 1];
    float s = w0.x * z0.x + w0.y * z0.y + w0.z * z0.z + w0.w * z0.w
            + w1.x * z1.x + w1.y * z1.y + w1.z * z1.z + w1.w * z1.w;
#pragma unroll
    for (int m = 1; m < 64; m <<= 1) s += __shfl_xor(s, m);
    if (ln == 0)
      proto_t[((size_t)b * NP + p) * DDIM + h * HDIM + j] = s * Linv;
  }
}

// ---------------- topk_mean: proto scores, stable top-k, mean -> zbuf[b][512] --
__global__ __launch_bounds__(256) void topk_mean(
    const float* __restrict__ proto_t, float* __restrict__ zbuf)
{
  const int b = blockIdx.x, tid = threadIdx.x;
  __shared__ float pt[NP][DDIM];
  __shared__ float spart[NP][8];
  __shared__ float sc[NP];
  __shared__ int sel[NP];
  for (int i = tid; i < NP * DDIM; i += 256) pt[i >> 9][i & 511] = proto_t[(size_t)b * NP * DDIM + i];
  __syncthreads();
  {
    int p = tid >> 3, pr = tid & 7;
    if (p < NP) {
      float s = 0.f;
      for (int k = 0; k < 64; ++k) { float v = pt[p][pr * 64 + k]; s += v * v; }
      spart[p][pr] = s;
    }
  }
  __syncthreads();
  if (tid < NP) {
    float s = 0.f;
    for (int k = 0; k < 8; ++k) s += spart[tid][k];
    sc[tid] = s;
  }
  __syncthreads();
  if (tid < NP) {
    float sv = sc[tid]; int rank = 0;
    for (int q = 0; q < NP; ++q) { float so = sc[q]; if (so > sv || (so == sv && q < tid)) ++rank; }
    sel[tid] = (rank < NTOPK) ? 1 : 0;
  }
  __syncthreads();
#pragma unroll
  for (int i = 0; i < 2; ++i) {
    const int d = tid + i * 256;
    float z0 = 0.f;
#pragma unroll
    for (int p = 0; p < NP; ++p)
      if (sel[p]) z0 += pt[p][d];
    zbuf[(size_t)b * DDIM + d] = z0 * (1.f / NTOPK);
  }
}

// ---------------- mlp_fc<ACT>: out[b][j] = act(zin[b] . W[j] + bias[j]) --------
template <int ACT>
__global__ __launch_bounds__(256) void mlp_fc(
    const float* __restrict__ zin, const float* __restrict__ W,
    const float* __restrict__ bias, float* __restrict__ outp)
{
  const int tid = threadIdx.x;
  const int wv = tid >> 6, ln = tid & 63;
  const int j = blockIdx.x * 4 + wv;
  __shared__ __align__(16) float zs[BB][DDIM];   // 16 KB
  for (int i = tid; i < BB * DDIM; i += 256) zs[i >> 9][i & 511] = zin[i];
  __syncthreads();
  const float4* wrow = reinterpret_cast<const float4*>(W + (size_t)j * DDIM);
  const float4 w0 = wrow[2 * ln], w1 = wrow[2 * ln + 1];
  const float bj = bias[j];
#pragma unroll
  for (int b = 0; b < BB; ++b) {
    const float4* zp = reinterpret_cast<const float4*>(zs[b]);
    float4 z0 = zp[2 * ln], z1 = zp[2 * ln + 1];
    float s = w0.x * z0.x + w0.y * z0.y + w0.z * z0.z + w0.w * z0.w
            + w1.x * z1.x + w1.y * z1.y + w1.z * z1.z + w1.w * z1.w;
#pragma unroll
    for (int m = 1; m < 64; m <<= 1) s += __shfl_xor(s, m);
    if (ln == b) {
      s += bj;
      if (ACT) s = s / (1.f + expf(-s));
      outp[(size_t)b * DDIM + j] = s;
    }
  }
}

extern "C" void kernel_launch(void* const* d_in, const int* in_sizes, int n_in,
                              void* d_out, int out_size, void* d_ws, size_t ws_size,
                              hipStream_t stream)
{
  const float* x    = (const float*)d_in[0];
  const float* prt  = (const float*)d_in[1];
  const float* ln_g = (const float*)d_in[2];
  const float* ln_b = (const float*)d_in[3];
  const float* Wq   = (const float*)d_in[4];
  const float* Wk   = (const float*)d_in[5];
  const float* Wv   = (const float*)d_in[6];
  const float* W1   = (const float*)d_in[7];
  const float* b1   = (const float*)d_in[8];
  const float* W2   = (const float*)d_in[9];
  const float* b2   = (const float*)d_in[10];
  float* out = (float*)d_out;
  float* ws = (float*)d_ws;

  float* qhs = ws;                                 // 12288
  float* ml  = ws + 12288;                         // 65536
  _Float16* xb16 = (_Float16*)(ws + 77824);        // 16777216 halves
  float* pt  = ws + 8466432;                       // 98304
  _Float16* wg16   = (_Float16*)(ws + 8564736);    // 262144 halves
  _Float16* wqkg16 = (_Float16*)(ws + 8695808);    // 65536 halves
  float* uvK     = ws + 9121792;                   // 512
  float* vvK     = ws + 9122304;                   // 512
  float* uq      = ws + 9122816;                   // 128
  float* vq      = ws + 9122944;                   // 128
  float* zbuf    = ws + 9123072;                   // 4096
  float* hbuf    = ws + 9127168;                   // 4096

  qh_kernel<<<NP, 256, 0, stream>>>(prt, Wq, qhs);
  wg16_kernel<<<512, 256, 0, stream>>>(Wk, ln_g, ln_b, wg16, uvK, vvK);
  wqkg_kernel<<<128, 256, 0, stream>>>(qhs, Wk, ln_g, ln_b, wqkg16, uq, vq);
  attn7<<<BB * 2 * NCHUNK, 512, 0, stream>>>(x, wg16, wqkg16, uvK, vvK, uq, vq,
                                             ln_g, ln_b, ml, xb16);
  reduce_proto<<<BB * NH * NP, 256, 0, stream>>>(ml, xb16, Wv, pt);
  topk_mean<<<BB, 256, 0, stream>>>(pt, zbuf);
  mlp_fc<1><<<128, 256, 0, stream>>>(zbuf, W1, b1, hbuf);
  mlp_fc<0><<<128, 256, 0, stream>>>(hbuf, W2, b2, out);
}

// Round 14
// 228.904 us; speedup vs baseline: 1.5534x; 1.5534x over previous
//
#include <hip/hip_runtime.h>
#include <hip/hip_bf16.h>

#define BB 8
#define TSEQ 8192
#define DDIM 512
#define NH 4
#define HDIM 128
#define NP 24
#define NPAD 32
#define NTOPK 12
#define NCHUNK 16
#define TCHUNK 512
#define NTILES 16

typedef _Float16 half8_t __attribute__((ext_vector_type(8)));
typedef _Float16 half4_t __attribute__((ext_vector_type(4)));
typedef _Float16 half2_t __attribute__((ext_vector_type(2)));
typedef float f32x4_t __attribute__((ext_vector_type(4)));

#define MFMA(a, b, c) __builtin_amdgcn_mfma_f32_16x16x32_f16((a), (b), (c), 0, 0, 0)

// LDS-only barrier: keeps global loads in flight across phases.
#define WGBAR() do { asm volatile("s_waitcnt lgkmcnt(0)" ::: "memory"); \
                     __builtin_amdgcn_s_barrier(); } while (0)

// ws layout (f32 units), total 4510976 f32 = 18 MB:
// qhs@0(12288) ml@12288(32768) xbar16@45056(4194304 f32 = 8388608 f16)
// pt@4239360(98304) wg16@4337664(131072) wqkg16@4468736(32768)
// normINV@4501504? -- no: normINV/miv below
// uvK@4501504(512) vvK@4502016(512) uq@4502528(128) vq@4502656(128)
// zbuf@4502784(4096) hbuf@4506880(4096)
// normINV@4510976(262144) miv@4773120(131072)  -> total 4904192 f32 = 19.6 MB

// ---------------- Qh precompute ----------------
__global__ __launch_bounds__(256) void qh_kernel(
    const float* __restrict__ proto, const float* __restrict__ Wq, float* __restrict__ qhs)
{
  const int p = blockIdx.x, tid = threadIdx.x;
  __shared__ float prow[DDIM];
  __shared__ float qp[DDIM];
  __shared__ float np[NH][8];
  __shared__ float nb[NH];
  prow[tid] = proto[(size_t)p * DDIM + tid];
  prow[tid + 256] = proto[(size_t)p * DDIM + tid + 256];
  __syncthreads();
#pragma unroll
  for (int i = 0; i < 2; ++i) {
    int dd = tid + i * 256;
    const float4* w4 = reinterpret_cast<const float4*>(Wq + (size_t)dd * DDIM);
    const float4* p4 = reinterpret_cast<const float4*>(prow);
    float s = 0.f;
    for (int d = 0; d < 128; ++d) {
      float4 av = p4[d], bv = w4[d];
      s += av.x * bv.x + av.y * bv.y + av.z * bv.z + av.w * bv.w;
    }
    qp[dd] = s;
  }
  __syncthreads();
  {
    int hh = tid >> 3, pr = tid & 7;
    if (hh < NH) {
      float s = 0.f;
      for (int k = 0; k < 16; ++k) { float v = qp[hh * HDIM + pr * 16 + k]; s += v * v; }
      np[hh][pr] = s;
    }
  }
  __syncthreads();
  if (tid < NH) {
    float s = 0.f;
    for (int k = 0; k < 8; ++k) s += np[tid][k];
    nb[tid] = 1.f / (fmaxf(sqrtf(s), 1e-12f) * 0.07f);
  }
  __syncthreads();
#pragma unroll
  for (int i = 0; i < 2; ++i) {
    int dd = tid + i * 256;
    int hh = dd >> 7, jj = dd & 127;
    qhs[((size_t)hh * NP + p) * HDIM + jj] = qp[dd] * nb[hh];
  }
}

// ---------------- wg16 = Wk*g (f16); u[j]=Wk.g, v[j]=Wk.b (f32) ----------------
__global__ __launch_bounds__(256) void wg16_kernel(
    const float* __restrict__ Wk, const float* __restrict__ ln_g, const float* __restrict__ ln_b,
    _Float16* __restrict__ wg16, float* __restrict__ uvK, float* __restrict__ vvK)
{
  const int j = blockIdx.x, tid = threadIdx.x;
  __shared__ float su[256], sv[256];
  float w0 = Wk[(size_t)j * 512 + tid], w1 = Wk[(size_t)j * 512 + tid + 256];
  float g0 = ln_g[tid], g1 = ln_g[tid + 256];
  float b0 = ln_b[tid], b1 = ln_b[tid + 256];
  wg16[(size_t)j * 512 + tid] = (_Float16)(w0 * g0);
  wg16[(size_t)j * 512 + tid + 256] = (_Float16)(w1 * g1);
  su[tid] = w0 * g0 + w1 * g1;
  sv[tid] = w0 * b0 + w1 * b1;
  __syncthreads();
  for (int s = 128; s > 0; s >>= 1) {
    if (tid < s) { su[tid] += su[tid + s]; sv[tid] += sv[tid + s]; }
    __syncthreads();
  }
  if (tid == 0) { uvK[j] = su[0]; vvK[j] = sv[0]; }
}

// ---------------- wqkg16 = (qhs@Wk)*g (f16); uq,vq reductions ----------------
__global__ __launch_bounds__(256) void wqkg_kernel(
    const float* __restrict__ qhs, const float* __restrict__ Wk,
    const float* __restrict__ ln_g, const float* __restrict__ ln_b,
    _Float16* __restrict__ wqkg16, float* __restrict__ uq, float* __restrict__ vq)
{
  const int blk = blockIdx.x, tid = threadIdx.x;
  const int p = blk & 31, h = blk >> 5;
  __shared__ float su[256], sv[256];
  if (p >= NP) {
    wqkg16[((size_t)(h * 32 + p)) * 512 + tid] = (_Float16)0.f;
    wqkg16[((size_t)(h * 32 + p)) * 512 + tid + 256] = (_Float16)0.f;
    if (tid == 0) { uq[h * 32 + p] = 0.f; vq[h * 32 + p] = 0.f; }
    return;
  }
  __shared__ float qv[HDIM];
  if (tid < HDIM) qv[tid] = qhs[((size_t)h * NP + p) * HDIM + tid];
  __syncthreads();
  float s0 = 0.f, s1 = 0.f;
  for (int j = 0; j < HDIM; ++j) {
    float q = qv[j];
    const float* wr = Wk + (size_t)(h * 128 + j) * 512;
    s0 += q * wr[tid];
    s1 += q * wr[tid + 256];
  }
  float g0 = ln_g[tid], g1 = ln_g[tid + 256];
  float b0 = ln_b[tid], b1 = ln_b[tid + 256];
  wqkg16[((size_t)(h * 32 + p)) * 512 + tid] = (_Float16)(s0 * g0);
  wqkg16[((size_t)(h * 32 + p)) * 512 + tid + 256] = (_Float16)(s1 * g1);
  su[tid] = s0 * g0 + s1 * g1;
  sv[tid] = s0 * b0 + s1 * b1;
  __syncthreads();
  for (int s = 128; s > 0; s >>= 1) {
    if (tid < s) { su[tid] += su[tid + s]; sv[tid] += sv[tid + s]; }
    __syncthreads();
  }
  if (tid == 0) { uq[h * 32 + p] = su[0]; vq[h * 32 + p] = sv[0]; }
}

// ---------------- knorm6: raw-x GEMM with register-resident Wg, LN-commuted ----
// grid [b8][g2 2][tc16] = 256 blocks (1/CU, 1 round), 512 thr. 512 tokens/block.
__global__ __launch_bounds__(512, 1) void knorm6(
    const float* __restrict__ x, const _Float16* __restrict__ wg16,
    const float* __restrict__ uvK, const float* __restrict__ vvK,
    float* __restrict__ normINV, float* __restrict__ miv)
{
  const int tid = threadIdx.x;
  const int w = tid >> 6, l = tid & 63;
  const int g = l >> 4, a = l & 15;
  const int blk = blockIdx.x;
  const int tc = blk & 15, g2 = (blk >> 4) & 1, b = blk >> 5;
  const int ct0 = tc * TCHUNK;

  __shared__ __align__(16) unsigned char xs_raw[32 * 1040];   // [32 t][520 f16] raw x
  __shared__ float normp_s[8][32];
  __shared__ float2 miv_s[32];

  const int jrow0 = g2 * 256 + 32 * w + a;
  half8_t wgf[2][16];
#pragma unroll
  for (int kst = 0; kst < 16; ++kst) {
    wgf[0][kst] = *reinterpret_cast<const half8_t*>(wg16 + (size_t)jrow0 * 512 + kst * 32 + g * 8);
    wgf[1][kst] = *reinterpret_cast<const half8_t*>(wg16 + (size_t)(jrow0 + 16) * 512 + kst * 32 + g * 8);
  }
  const float u0 = uvK[jrow0], u1 = uvK[jrow0 + 16];
  const float v0 = vvK[jrow0], v1 = vvK[jrow0 + 16];

  const float4* xc4 = reinterpret_cast<const float4*>(x) + ((size_t)(b * TSEQ + ct0)) * 128;

  float4 praw[4][2];
#pragma unroll
  for (int tt = 0; tt < 4; ++tt)
#pragma unroll
    for (int i = 0; i < 2; ++i)
      praw[tt][i] = xc4[(size_t)(4 * w + tt) * 128 + l + 64 * i];

  for (int tile = 0; tile < NTILES; ++tile) {
    float sA[4], sB[4];
#pragma unroll
    for (int tt = 0; tt < 4; ++tt) {
      float4 v0f = praw[tt][0], v1f = praw[tt][1];
      sA[tt] = (v0f.x + v0f.y) + (v0f.z + v0f.w) + (v1f.x + v1f.y) + (v1f.z + v1f.w);
      sB[tt] = (v0f.x * v0f.x + v0f.y * v0f.y) + (v0f.z * v0f.z + v0f.w * v0f.w)
             + (v1f.x * v1f.x + v1f.y * v1f.y) + (v1f.z * v1f.z + v1f.w * v1f.w);
    }
#pragma unroll
    for (int m = 1; m < 64; m <<= 1)
#pragma unroll
      for (int tt = 0; tt < 4; ++tt) { sA[tt] += __shfl_xor(sA[tt], m); sB[tt] += __shfl_xor(sB[tt], m); }
    float muv[4], ivv[4];
#pragma unroll
    for (int tt = 0; tt < 4; ++tt) {
      float mu = sA[tt] * (1.f / 512.f);
      float var = sB[tt] * (1.f / 512.f) - mu * mu;
      muv[tt] = mu; ivv[tt] = rsqrtf(var + 1e-5f);
    }

    WGBAR();   // barA

#pragma unroll
    for (int tt = 0; tt < 4; ++tt)
#pragma unroll
      for (int i = 0; i < 2; ++i) {
        float4 v = praw[tt][i];
        half4_t hx;
        hx[0] = (_Float16)v.x; hx[1] = (_Float16)v.y; hx[2] = (_Float16)v.z; hx[3] = (_Float16)v.w;
        *reinterpret_cast<half4_t*>(xs_raw + (4 * w + tt) * 1040 + 8 * l + 512 * i) = hx;
      }
#pragma unroll
    for (int tt = 0; tt < 4; ++tt) {
      if (l == tt) {
        miv_s[4 * w + tt] = make_float2(muv[tt], ivv[tt]);
        if (g2 == 0) {
          size_t t = (size_t)b * TSEQ + ct0 + tile * 32 + 4 * w + tt;
          miv[2 * t] = muv[tt];
          miv[2 * t + 1] = ivv[tt];
        }
      }
    }
    if (tile + 1 < NTILES) {
#pragma unroll
      for (int tt = 0; tt < 4; ++tt)
#pragma unroll
        for (int i = 0; i < 2; ++i)
          praw[tt][i] = xc4[(size_t)((tile + 1) * 32 + 4 * w + tt) * 128 + l + 64 * i];
    }
    WGBAR();   // barB

    f32x4_t kacc[2][2];
    const f32x4_t vzero = {0.f, 0.f, 0.f, 0.f};
    kacc[0][0] = vzero; kacc[0][1] = vzero; kacc[1][0] = vzero; kacc[1][1] = vzero;
#pragma unroll
    for (int kst = 0; kst < 16; ++kst) {
#pragma unroll
      for (int mt = 0; mt < 2; ++mt) {
        half8_t af = *reinterpret_cast<const half8_t*>(xs_raw + (16 * mt + a) * 1040 + kst * 64 + g * 16);
        kacc[mt][0] = MFMA(af, wgf[0][kst], kacc[mt][0]);
        kacc[mt][1] = MFMA(af, wgf[1][kst], kacc[mt][1]);
      }
    }
    float np2[2][4];
#pragma unroll
    for (int mt = 0; mt < 2; ++mt)
#pragma unroll
      for (int r = 0; r < 4; ++r) {
        float2 mvt = miv_s[16 * mt + 4 * g + r];
        float k0 = mvt.y * (kacc[mt][0][r] - mvt.x * u0) + v0;
        float k1 = mvt.y * (kacc[mt][1][r] - mvt.x * u1) + v1;
        np2[mt][r] = k0 * k0 + k1 * k1;
      }
#pragma unroll
    for (int m = 1; m < 16; m <<= 1)
#pragma unroll
      for (int mt = 0; mt < 2; ++mt)
#pragma unroll
        for (int r = 0; r < 4; ++r) np2[mt][r] += __shfl_xor(np2[mt][r], m);
    if (a == 0) {
#pragma unroll
      for (int mt = 0; mt < 2; ++mt)
#pragma unroll
        for (int r = 0; r < 4; ++r) normp_s[w][16 * mt + 4 * g + r] = np2[mt][r];
    }
    WGBAR();   // barC
    if (tid < 64) {
      const int t = tid & 31, hl = tid >> 5;
      float s = normp_s[hl * 4 + 0][t] + normp_s[hl * 4 + 1][t]
              + normp_s[hl * 4 + 2][t] + normp_s[hl * 4 + 3][t];
      normINV[((size_t)b * NH + 2 * g2 + hl) * TSEQ + ct0 + tile * 32 + t] =
          rsqrtf(fmaxf(s, 1e-24f));
    }
  }
}

// ---------------- attn6: raw-x staging, LN-commuted scores + accumulate ----
// grid [b8][g2 2][c16] = 256 blocks, 512 thr, 512 tokens/block.
__global__ __launch_bounds__(512, 1) void attn6(
    const float* __restrict__ x, const _Float16* __restrict__ wqkg16,
    const float* __restrict__ normINV, const float* __restrict__ miv,
    const float* __restrict__ uq, const float* __restrict__ vq,
    const float* __restrict__ ln_g, const float* __restrict__ ln_b,
    float* __restrict__ ml, _Float16* __restrict__ xbar)
{
  const int tid = threadIdx.x;
  const int w = tid >> 6, l = tid & 63;
  const int g = l >> 4, a = l & 15;
  const int blk = blockIdx.x;
  const int c = blk & 15, g2 = (blk >> 4) & 1, b = blk >> 5;

  __shared__ __align__(16) unsigned char xs_raw[32 * 1040];
  __shared__ __align__(16) unsigned char xt_raw[512 * 72];
  __shared__ __align__(16) unsigned char wl_raw[64 * 80];
  __shared__ float mArr_s[64], lArr_s[64], fbuf_s[64], c1Arr_s[64];

  if (tid < 64) { mArr_s[tid] = -1e30f; lArr_s[tid] = 0.f; c1Arr_s[tid] = 0.f; }

  f32x4_t acc3[4][4];
  const f32x4_t vzero = {0.f, 0.f, 0.f, 0.f};
#pragma unroll
  for (int mA = 0; mA < 4; ++mA)
#pragma unroll
    for (int nt = 0; nt < 4; ++nt) acc3[mA][nt] = vzero;

  const float4* xc4 = reinterpret_cast<const float4*>(x) + ((size_t)(b * TSEQ + c * TCHUNK)) * 128;
  const _Float16* wqbase = wqkg16 + ((size_t)(g2 * 64 + 16 * w + a)) * 512 + g * 8;
  const float* nbase0 = normINV + ((size_t)b * NH + 2 * g2 + (w >> 1)) * TSEQ + c * TCHUNK;
  const float* mivc = miv + 2 * ((size_t)b * TSEQ + c * TCHUNK);
  float uqp = 0.f, vqp = 0.f;
  if (w < 4) { uqp = uq[g2 * 64 + 16 * w + a]; vqp = vq[g2 * 64 + 16 * w + a]; }

  float4 praw[4][2];
#pragma unroll
  for (int tt = 0; tt < 4; ++tt)
#pragma unroll
    for (int i = 0; i < 2; ++i)
      praw[tt][i] = xc4[(size_t)(4 * w + tt) * 128 + l + 64 * i];

  for (int tile = 0; tile < NTILES; ++tile) {
    WGBAR();   // barA

#pragma unroll
    for (int tt = 0; tt < 4; ++tt)
#pragma unroll
      for (int i = 0; i < 2; ++i) {
        float4 v = praw[tt][i];
        half4_t hx;
        hx[0] = (_Float16)v.x; hx[1] = (_Float16)v.y; hx[2] = (_Float16)v.z; hx[3] = (_Float16)v.w;
        *reinterpret_cast<half4_t*>(xs_raw + (4 * w + tt) * 1040 + 8 * l + 512 * i) = hx;
      }
    {
      const float* pf = reinterpret_cast<const float*>(praw);
#pragma unroll
      for (int i = 0; i < 2; ++i)
#pragma unroll
        for (int e = 0; e < 4; ++e) {
          half4_t hv;
          hv[0] = (_Float16)pf[0 * 8 + i * 4 + e];
          hv[1] = (_Float16)pf[1 * 8 + i * 4 + e];
          hv[2] = (_Float16)pf[2 * 8 + i * 4 + e];
          hv[3] = (_Float16)pf[3 * 8 + i * 4 + e];
          int d = 4 * l + 256 * i + e;
          *reinterpret_cast<half4_t*>(xt_raw + d * 72 + 8 * (w ^ ((d >> 4) & 7))) = hv;
        }
    }
    if (tile + 1 < NTILES) {
#pragma unroll
      for (int tt = 0; tt < 4; ++tt)
#pragma unroll
        for (int i = 0; i < 2; ++i)
          praw[tt][i] = xc4[(size_t)((tile + 1) * 32 + 4 * w + tt) * 128 + l + 64 * i];
    }
    f32x4_t niv4[2];
    f32x4_t mv[2][2];
    if (w < 4) {
      const float* nb2 = nbase0 + tile * 32 + 4 * g;
      niv4[0] = *reinterpret_cast<const f32x4_t*>(nb2);
      niv4[1] = *reinterpret_cast<const f32x4_t*>(nb2 + 16);
#pragma unroll
      for (int mt = 0; mt < 2; ++mt) {
        const float* mb = mivc + 2 * (tile * 32 + 16 * mt + 4 * g);
        mv[mt][0] = *reinterpret_cast<const f32x4_t*>(mb);
        mv[mt][1] = *reinterpret_cast<const f32x4_t*>(mb + 4);
      }
    }
    WGBAR();   // barB

    if (w < 4) {
      f32x4_t qacc[2] = {vzero, vzero};
#pragma unroll
      for (int kst = 0; kst < 16; ++kst) {
        half8_t bq8 = *reinterpret_cast<const half8_t*>(wqbase + kst * 32);
#pragma unroll
        for (int mt = 0; mt < 2; ++mt) {
          half8_t af = *reinterpret_cast<const half8_t*>(xs_raw + (16 * mt + a) * 1040 + kst * 64 + g * 16);
          qacc[mt] = MFMA(af, bq8, qacc[mt]);
        }
      }
      const int p = 16 * w + a;
      float sc[2][4], ivr[2][4], imr[2][4];
      float cmax = -3e38f;
#pragma unroll
      for (int mt = 0; mt < 2; ++mt)
#pragma unroll
        for (int r = 0; r < 4; ++r) {
          float mu = mv[mt][r >> 1][2 * (r & 1)];
          float iv = mv[mt][r >> 1][2 * (r & 1) + 1];
          ivr[mt][r] = iv;
          imr[mt][r] = iv * mu;
          float s = (iv * (qacc[mt][r] - mu * uqp) + vqp) * niv4[mt][r];
          sc[mt][r] = s;
          cmax = fmaxf(cmax, s);
        }
      cmax = fmaxf(cmax, __shfl_xor(cmax, 16));
      cmax = fmaxf(cmax, __shfl_xor(cmax, 32));
      float mo = mArr_s[p];
      float mn = fmaxf(mo, cmax);
      float fe = __expf(mo - mn);
      float ls = 0.f, ls1 = 0.f;
#pragma unroll
      for (int mt = 0; mt < 2; ++mt) {
        half4_t wp;
#pragma unroll
        for (int r = 0; r < 4; ++r) {
          float e = __expf(sc[mt][r] - mn);
          ls += e;
          ls1 += e * imr[mt][r];
          wp[r] = (_Float16)(e * ivr[mt][r]);
        }
        *reinterpret_cast<half4_t*>(wl_raw + p * 80 + 32 * mt + 8 * g) = wp;
      }
      ls += __shfl_xor(ls, 16);   ls += __shfl_xor(ls, 32);
      ls1 += __shfl_xor(ls1, 16); ls1 += __shfl_xor(ls1, 32);
      if (l < 16) {
        mArr_s[p] = mn;
        lArr_s[p] = lArr_s[p] * fe + ls;
        c1Arr_s[p] = c1Arr_s[p] * fe + ls1;
        fbuf_s[p] = fe;
      }
    }
    WGBAR();   // barE

#pragma unroll
    for (int mA = 0; mA < 4; ++mA)
#pragma unroll
      for (int r = 0; r < 4; ++r) {
        float f = fbuf_s[16 * mA + 4 * g + r];
#pragma unroll
        for (int nt = 0; nt < 4; ++nt) acc3[mA][nt][r] *= f;
      }
    {
      half8_t wlf[4];
#pragma unroll
      for (int mA = 0; mA < 4; ++mA)
        wlf[mA] = *reinterpret_cast<const half8_t*>(wl_raw + (16 * mA + a) * 80 + 16 * g);
#pragma unroll
      for (int nt = 0; nt < 4; ++nt) {
        const int d = 64 * w + 16 * nt + a;
        const unsigned char* rowp = xt_raw + d * 72;
        const int key = (d >> 4) & 7;
        half4_t lo = *reinterpret_cast<const half4_t*>(rowp + 8 * ((2 * g) ^ key));
        half4_t hi = *reinterpret_cast<const half4_t*>(rowp + 8 * ((2 * g + 1) ^ key));
        half8_t bf;
        bf[0] = lo[0]; bf[1] = lo[1]; bf[2] = lo[2]; bf[3] = lo[3];
        bf[4] = hi[0]; bf[5] = hi[1]; bf[6] = hi[2]; bf[7] = hi[3];
#pragma unroll
        for (int mA = 0; mA < 4; ++mA) acc3[mA][nt] = MFMA(wlf[mA], bf, acc3[mA][nt]);
      }
    }
  }

  __syncthreads();
  float gd[4], bd[4];
#pragma unroll
  for (int nt = 0; nt < 4; ++nt) {
    gd[nt] = ln_g[64 * w + 16 * nt + a];
    bd[nt] = ln_b[64 * w + 16 * nt + a];
  }
#pragma unroll
  for (int mA = 0; mA < 4; ++mA)
#pragma unroll
    for (int r = 0; r < 4; ++r) {
      const int p = 16 * mA + 4 * g + r;
      const float c1p = c1Arr_s[p], lp = lArr_s[p];
      const int h = 2 * g2 + (p >> 5), ph = p & 31;
      _Float16* xb = xbar + ((((size_t)b * NH + h) * NCHUNK + c) * NPAD + ph) * DDIM;
#pragma unroll
      for (int nt = 0; nt < 4; ++nt)
        xb[64 * w + 16 * nt + a] = (_Float16)(gd[nt] * (acc3[mA][nt][r] - c1p) + bd[nt] * lp);
    }
  if (tid < 64) {
    const int h = 2 * g2 + (tid >> 5), ph = tid & 31;
    size_t mlb = ((((size_t)b * NH + h) * NCHUNK + c) * NPAD + ph) * 2;
    ml[mlb] = mArr_s[tid];
    ml[mlb + 1] = lArr_s[tid];
  }
}

// ---------------- combine chunk partials, apply Wv (coalesced wave-dot) --------
__global__ __launch_bounds__(256) void reduce_proto(
    const float* __restrict__ ml, const _Float16* __restrict__ xbar,
    const float* __restrict__ Wv, float* __restrict__ proto_t)
{
  const int tid = threadIdx.x;
  const int blk = blockIdx.x;
  const int p = blk % NP;
  const int h = (blk / NP) % NH;
  const int b = blk / (NP * NH);
  const int wv = tid >> 6, ln = tid & 63;

  __shared__ float fch[NCHUNK];
  __shared__ float LinvS;
  __shared__ __align__(16) float xbs[DDIM];

  if (tid < NCHUNK) {
    size_t idx = ((((size_t)b * NH + h) * NCHUNK + tid) * NPAD + p) * 2;
    float m = ml[idx], lv = ml[idx + 1];
    float mstar = m;
#pragma unroll
    for (int k = NCHUNK / 2; k >= 1; k >>= 1) mstar = fmaxf(mstar, __shfl_xor(mstar, k));
    float f = __expf(m - mstar);
    float Lp = lv * f;
#pragma unroll
    for (int k = NCHUNK / 2; k >= 1; k >>= 1) Lp += __shfl_xor(Lp, k);
    fch[tid] = f;
    if (tid == 0) LinvS = 1.f / fmaxf(Lp, 1e-30f);
  }
  __syncthreads();
  float a0 = 0.f, a1 = 0.f;
  for (int cc = 0; cc < NCHUNK; ++cc) {
    float f = fch[cc];
    const _Float16* src = xbar + ((((size_t)b * NH + h) * NCHUNK + cc) * NPAD + p) * DDIM;
    half2_t v = *reinterpret_cast<const half2_t*>(src + 2 * tid);
    a0 += f * (float)v[0];
    a1 += f * (float)v[1];
  }
  xbs[2 * tid] = a0;
  xbs[2 * tid + 1] = a1;
  __syncthreads();
  const float Linv = LinvS;
  const float4* zp = reinterpret_cast<const float4*>(xbs);
  const float4 z0 = zp[2 * ln], z1 = zp[2 * ln + 1];
#pragma unroll 4
  for (int j0 = 0; j0 < 32; ++j0) {
    const int j = wv * 32 + j0;
    const float4* wrow = reinterpret_cast<const float4*>(Wv + (size_t)(h * HDIM + j) * DDIM);
    float4 w0 = wrow[2 * ln], w1 = wrow[2 * ln + 1];
    float s = w0.x * z0.x + w0.y * z0.y + w0.z * z0.z + w0.w * z0.w
            + w1.x * z1.x + w1.y * z1.y + w1.z * z1.z + w1.w * z1.w;
#pragma unroll
    for (int m = 1; m < 64; m <<= 1) s += __shfl_xor(s, m);
    if (ln == 0)
      proto_t[((size_t)b * NP + p) * DDIM + h * HDIM + j] = s * Linv;
  }
}

// ---------------- topk_mean: proto scores, stable top-k, mean -> zbuf[b][512] --
__global__ __launch_bounds__(256) void topk_mean(
    const float* __restrict__ proto_t, float* __restrict__ zbuf)
{
  const int b = blockIdx.x, tid = threadIdx.x;
  __shared__ float pt[NP][DDIM];
  __shared__ float spart[NP][8];
  __shared__ float sc[NP];
  __shared__ int sel[NP];
  for (int i = tid; i < NP * DDIM; i += 256) pt[i >> 9][i & 511] = proto_t[(size_t)b * NP * DDIM + i];
  __syncthreads();
  {
    int p = tid >> 3, pr = tid & 7;
    if (p < NP) {
      float s = 0.f;
      for (int k = 0; k < 64; ++k) { float v = pt[p][pr * 64 + k]; s += v * v; }
      spart[p][pr] = s;
    }
  }
  __syncthreads();
  if (tid < NP) {
    float s = 0.f;
    for (int k = 0; k < 8; ++k) s += spart[tid][k];
    sc[tid] = s;
  }
  __syncthreads();
  if (tid < NP) {
    float sv = sc[tid]; int rank = 0;
    for (int q = 0; q < NP; ++q) { float so = sc[q]; if (so > sv || (so == sv && q < tid)) ++rank; }
    sel[tid] = (rank < NTOPK) ? 1 : 0;
  }
  __syncthreads();
#pragma unroll
  for (int i = 0; i < 2; ++i) {
    const int d = tid + i * 256;
    float z0 = 0.f;
#pragma unroll
    for (int p = 0; p < NP; ++p)
      if (sel[p]) z0 += pt[p][d];
    zbuf[(size_t)b * DDIM + d] = z0 * (1.f / NTOPK);
  }
}

// ---------------- mlp_fc<ACT>: out[b][j] = act(zin[b] . W[j] + bias[j]) --------
template <int ACT>
__global__ __launch_bounds__(256) void mlp_fc(
    const float* __restrict__ zin, const float* __restrict__ W,
    const float* __restrict__ bias, float* __restrict__ outp)
{
  const int tid = threadIdx.x;
  const int wv = tid >> 6, ln = tid & 63;
  const int j = blockIdx.x * 4 + wv;
  __shared__ __align__(16) float zs[BB][DDIM];   // 16 KB
  for (int i = tid; i < BB * DDIM; i += 256) zs[i >> 9][i & 511] = zin[i];
  __syncthreads();
  const float4* wrow = reinterpret_cast<const float4*>(W + (size_t)j * DDIM);
  const float4 w0 = wrow[2 * ln], w1 = wrow[2 * ln + 1];
  const float bj = bias[j];
#pragma unroll
  for (int b = 0; b < BB; ++b) {
    const float4* zp = reinterpret_cast<const float4*>(zs[b]);
    float4 z0 = zp[2 * ln], z1 = zp[2 * ln + 1];
    float s = w0.x * z0.x + w0.y * z0.y + w0.z * z0.z + w0.w * z0.w
            + w1.x * z1.x + w1.y * z1.y + w1.z * z1.z + w1.w * z1.w;
#pragma unroll
    for (int m = 1; m < 64; m <<= 1) s += __shfl_xor(s, m);
    if (ln == b) {
      s += bj;
      if (ACT) s = s / (1.f + expf(-s));
      outp[(size_t)b * DDIM + j] = s;
    }
  }
}

extern "C" void kernel_launch(void* const* d_in, const int* in_sizes, int n_in,
                              void* d_out, int out_size, void* d_ws, size_t ws_size,
                              hipStream_t stream)
{
  const float* x    = (const float*)d_in[0];
  const float* prt  = (const float*)d_in[1];
  const float* ln_g = (const float*)d_in[2];
  const float* ln_b = (const float*)d_in[3];
  const float* Wq   = (const float*)d_in[4];
  const float* Wk   = (const float*)d_in[5];
  const float* Wv   = (const float*)d_in[6];
  const float* W1   = (const float*)d_in[7];
  const float* b1   = (const float*)d_in[8];
  const float* W2   = (const float*)d_in[9];
  const float* b2   = (const float*)d_in[10];
  float* out = (float*)d_out;
  float* ws = (float*)d_ws;

  float* qhs = ws;                                 // 12288
  float* ml  = ws + 12288;                         // 32768 ([B][H][16][32][2])
  _Float16* xb16 = (_Float16*)(ws + 45056);        // 8388608 halves
  float* pt  = ws + 4239360;                       // 98304
  _Float16* wg16   = (_Float16*)(ws + 4337664);    // 262144 halves
  _Float16* wqkg16 = (_Float16*)(ws + 4468736);    // 65536 halves
  float* uvK     = ws + 4501504;                   // 512
  float* vvK     = ws + 4502016;                   // 512
  float* uq      = ws + 4502528;                   // 128
  float* vq      = ws + 4502656;                   // 128
  float* zbuf    = ws + 4502784;                   // 4096
  float* hbuf    = ws + 4506880;                   // 4096
  float* normINV = ws + 4510976;                   // 262144
  float* miv     = ws + 4773120;                   // 131072
  // total 4904192 f32 = 19.6 MB

  qh_kernel<<<NP, 256, 0, stream>>>(prt, Wq, qhs);
  wg16_kernel<<<512, 256, 0, stream>>>(Wk, ln_g, ln_b, wg16, uvK, vvK);
  wqkg_kernel<<<128, 256, 0, stream>>>(qhs, Wk, ln_g, ln_b, wqkg16, uq, vq);
  knorm6<<<BB * 2 * 16, 512, 0, stream>>>(x, wg16, uvK, vvK, normINV, miv);
  attn6<<<BB * 2 * NCHUNK, 512, 0, stream>>>(x, wqkg16, normINV, miv, uq, vq, ln_g, ln_b, ml, xb16);
  reduce_proto<<<BB * NH * NP, 256, 0, stream>>>(ml, xb16, Wv, pt);
  topk_mean<<<BB, 256, 0, stream>>>(pt, zbuf);
  mlp_fc<1><<<128, 256, 0, stream>>>(zbuf, W1, b1, hbuf);
  mlp_fc<0><<<128, 256, 0, stream>>>(hbuf, W2, b2, out);
}